// Round 2
// baseline (129.318 us; speedup 1.0000x reference)
//
#include <hip/hip_runtime.h>
#include <stdint.h>

// VectorQuantizer: x[32,64,64,64] NCHW fp32, W[512,64] fp32.
// dist = ||x||^2 + ||w||^2 - 2 x.w ; argmin over k; out = W[argmin] in NCHW.
//
// bf16 MFMA scores s_k = dot_bf16(x,w_k) - 0.5*||w_k||^2 (argmax s == argmin dist),
// margin-certified candidate set (score margin 0.75 >> max bf16 err ~0.15),
// exact fp64 refine for multi-candidate tokens (~14%).

typedef short short8 __attribute__((ext_vector_type(8)));
typedef float f32x4 __attribute__((ext_vector_type(4)));

#define HW_ 4096
#define C_ 64
#define K_ 512
#define D_ 64

__device__ __forceinline__ unsigned short f2bf(float f) {
    unsigned u = __float_as_uint(f);
    u += 0x7fff + ((u >> 16) & 1);   // RNE to bf16
    return (unsigned short)(u >> 16);
}

__global__ __launch_bounds__(64) void vq_prep(const float* __restrict__ W,
                                              unsigned short* __restrict__ Wb,
                                              float* __restrict__ wsq) {
    int k = blockIdx.x;
    int l = threadIdx.x;
    float v = W[k * D_ + l];
    Wb[k * D_ + l] = f2bf(v);
    float s = v * v;
    #pragma unroll
    for (int off = 1; off < 64; off <<= 1) s += __shfl_xor(s, off);
    if (l == 0) wsq[k] = s;
}

__global__ __launch_bounds__(256, 2) void vq_main(const float* __restrict__ x,
                                                  const float* __restrict__ W,
                                                  const unsigned short* __restrict__ Wb,
                                                  const float* __restrict__ wsq,
                                                  float* __restrict__ out) {
    __shared__ float Xf[64 * 65];   // [tok][d] pad 65; later reused as Qt [d][tok]
    __shared__ int bkArr[64];

    const int tid = threadIdx.x;
    const int bid = blockIdx.x;
    const int b = bid >> 6;                 // batch
    const int p0 = (bid & 63) << 6;         // position block (h*64+w)

    // ---- phase 0: load 64 tokens x 64 dims, transpose into LDS (coalesced reads) ----
    {
        const int p = tid & 63;
        const int c0 = tid >> 6;            // 0..3
        #pragma unroll
        for (int i = 0; i < 16; ++i) {
            int c = c0 + i * 4;
            Xf[p * 65 + c] = x[(size_t)(b * C_ + c) * HW_ + p0 + p];
        }
    }
    __syncthreads();

    const int l = tid & 63;                 // lane
    const int wv = tid >> 6;                // wave 0..3, owns tokens wv*16..wv*16+15
    const int g = l >> 4;                   // k-dim group 0..3
    const int tokw = l & 15;
    const int tok = wv * 16 + tokw;

    // B fragments: X[tok][d], d = s*32 + g*8 + e  (16x16x32 bf16 B layout)
    short8 bfrag[2];
    #pragma unroll
    for (int s = 0; s < 2; ++s) {
        #pragma unroll
        for (int e = 0; e < 8; ++e)
            bfrag[s][e] = (short)f2bf(Xf[tok * 65 + s * 32 + g * 8 + e]);
    }

    // ---- phase 1: 32 k-tiles of 16, acc[t][r] = score for k = t*16 + g*4 + r, token tokw ----
    f32x4 acc[32];
    const unsigned short* Abase = Wb + tokw * 64 + g * 8;  // A row = l&15, k-dim offset g*8
    #pragma unroll
    for (int t = 0; t < 32; ++t) {
        const f32x4 w4 = *(const f32x4*)(wsq + t * 16 + g * 4);
        f32x4 a = -0.5f * w4;               // C-init = -0.5*||w||^2
        short8 a0 = *(const short8*)(Abase + t * 16 * 64);
        short8 a1 = *(const short8*)(Abase + t * 16 * 64 + 32);
        a = __builtin_amdgcn_mfma_f32_16x16x32_bf16(a0, bfrag[0], a, 0, 0, 0);
        a = __builtin_amdgcn_mfma_f32_16x16x32_bf16(a1, bfrag[1], a, 0, 0, 0);
        acc[t] = a;
    }

    // ---- phase 2a: per-token max score (across 4 lanes sharing the token) ----
    float m = -3.4e38f;
    #pragma unroll
    for (int t = 0; t < 32; ++t)
        m = fmaxf(m, fmaxf(fmaxf(acc[t][0], acc[t][1]), fmaxf(acc[t][2], acc[t][3])));
    m = fmaxf(m, __shfl_xor(m, 16));
    m = fmaxf(m, __shfl_xor(m, 32));
    const float thr = m - 0.75f;            // dist margin 1.5 >> 2*max bf16 score err

    // ---- phase 2b: candidate masks ----
    uint64_t c0m = 0, c1m = 0;
    int cnt = 0;
    #pragma unroll
    for (int t = 0; t < 32; ++t) {
        #pragma unroll
        for (int r = 0; r < 4; ++r) {
            if (acc[t][r] >= thr) {
                ++cnt;
                if (t < 16) c0m |= 1ull << (t * 4 + r);
                else        c1m |= 1ull << ((t - 16) * 4 + r);
            }
        }
    }
    int cnt4 = cnt;
    cnt4 += __shfl_xor(cnt4, 16);
    cnt4 += __shfl_xor(cnt4, 32);

    // single-candidate fast path: that k is provably the exact argmin
    int klocal = 0x7fffffff;
    if (cnt == 1) {
        int slot = c0m ? __builtin_ctzll(c0m) : 64 + __builtin_ctzll(c1m);
        klocal = (slot >> 2) * 16 + g * 4 + (slot & 3);
    }
    int kmin = klocal;
    kmin = min(kmin, __shfl_xor(kmin, 16));
    kmin = min(kmin, __shfl_xor(kmin, 32));

    // multi-candidate path: exact fp64 distances sum((x-w)^2), wave-cooperative
    double bd = 1.0e308;
    int bkm = 0x7fffffff;
    const bool multi = (cnt4 > 1);
    if (!multi) { c0m = 0; c1m = 0; }
    uint64_t wmask = __ballot((c0m | c1m) != 0ull);
    while (wmask) {
        int L = __builtin_ctzll(wmask);
        wmask &= wmask - 1;
        uint64_t m0 = __shfl(c0m, L);
        uint64_t m1 = __shfl(c1m, L);
        int gL = L >> 4;
        int tokL = wv * 16 + (L & 15);
        double xv = (double)Xf[tokL * 65 + l];
        while (m0 | m1) {
            int k;
            if (m0) {
                int slot = __builtin_ctzll(m0); m0 &= m0 - 1;
                k = (slot >> 2) * 16 + gL * 4 + (slot & 3);
            } else {
                int slot = __builtin_ctzll(m1); m1 &= m1 - 1;
                k = ((slot >> 2) + 16) * 16 + gL * 4 + (slot & 3);
            }
            double dl = xv - (double)W[k * 64 + l];
            double p = dl * dl;
            #pragma unroll
            for (int off = 1; off < 64; off <<= 1) p += __shfl_xor(p, off);
            if (l == L && (p < bd || (p == bd && k < bkm))) { bd = p; bkm = k; }
        }
    }
    {   // lexicographic (dist, k) merge across the 4 lanes of each token
        double od = __shfl_xor(bd, 16); int ok = __shfl_xor(bkm, 16);
        if (od < bd || (od == bd && ok < bkm)) { bd = od; bkm = ok; }
        od = __shfl_xor(bd, 32); ok = __shfl_xor(bkm, 32);
        if (od < bd || (od == bd && ok < bkm)) { bd = od; bkm = ok; }
    }
    const int bk = multi ? bkm : kmin;

    if (g == 0) bkArr[wv * 16 + tokw] = bk;
    __syncthreads();

    // ---- output: gather W[bk] coalesced into LDS (as [d][tok]), then coalesced NCHW store ----
    {
        int tk = tid >> 2;
        int part = tid & 3;
        int k = bkArr[tk];
        #pragma unroll
        for (int j = 0; j < 4; ++j) {
            f32x4 v = *(const f32x4*)(W + k * 64 + part * 16 + j * 4);
            #pragma unroll
            for (int c = 0; c < 4; ++c)
                Xf[(part * 16 + j * 4 + c) * 65 + tk] = v[c];
        }
    }
    __syncthreads();
    {
        int p = tid & 63;
        int d0 = tid >> 6;
        #pragma unroll
        for (int i = 0; i < 16; ++i) {
            int d = i * 4 + d0;
            out[(size_t)(b * C_ + d) * HW_ + p0 + p] = Xf[d * 65 + p];
        }
    }
}

extern "C" void kernel_launch(void* const* d_in, const int* in_sizes, int n_in,
                              void* d_out, int out_size, void* d_ws, size_t ws_size,
                              hipStream_t stream) {
    const float* x = (const float*)d_in[0];
    const float* W = (const float*)d_in[1];
    unsigned short* Wb = (unsigned short*)d_ws;                 // 512*64 bf16 = 64 KiB
    float* wsq = (float*)((char*)d_ws + K_ * D_ * 2);           // 512 f32 = 2 KiB
    vq_prep<<<K_, 64, 0, stream>>>(W, Wb, wsq);
    vq_main<<<2048, 256, 0, stream>>>(x, W, Wb, wsq, (float*)d_out);
}

// Round 4
// 81.749 us; speedup vs baseline: 1.5819x; 1.5819x over previous
//
#include <hip/hip_runtime.h>
#include <stdint.h>

// VectorQuantizer: x[32,64,64,64] NCHW fp32, W[512,64] fp32.
// argmin_k ||x - w_k||^2 ; out = W[argmin] in NCHW.
//
// v3b: LDS-resident codebook (4 x 16KiB double-buffered chunks, XOR-swizzled),
// chunked bf16-MFMA scores packed to f16 (64 VGPRs for all 512 scores),
// margin-certified candidates (margin 1.125 >= 2*(mfma 0.375 + f16 0.125)),
// exact fp64 refine for multi-candidate tokens. 3 blocks/CU, 12 waves/CU.

typedef short short8 __attribute__((ext_vector_type(8)));
typedef float f32x4 __attribute__((ext_vector_type(4)));
typedef __fp16 h2 __attribute__((ext_vector_type(2)));

#define HW_ 4096
#define K_ 512
#define D_ 64
#define MARGIN 1.125f

__device__ __forceinline__ unsigned short f2bf(float f) {
    unsigned u = __float_as_uint(f);
    u += 0x7fff + ((u >> 16) & 1);   // RNE to bf16
    return (unsigned short)(u >> 16);
}

// ws image: Wb = swizzled bf16 codebook, 4 chunks of 128 codes.
// elem (k,d) -> chunk k>>7, slot (r*64+d) ^ ((r&7)<<3), r = k&127.
__global__ __launch_bounds__(64) void vq_prep(const float* __restrict__ W,
                                              unsigned short* __restrict__ Wb,
                                              float* __restrict__ nh) {
    int k = blockIdx.x, l = threadIdx.x;
    float v = W[k * D_ + l];
    int r = k & 127, ch = k >> 7;
    Wb[ch * 8192 + ((r * 64 + l) ^ ((r & 7) << 3))] = f2bf(v);
    float s = v * v;
    #pragma unroll
    for (int off = 1; off < 64; off <<= 1) s += __shfl_xor(s, off);
    if (l == 0) nh[k] = -0.5f * s;
}

__global__ __launch_bounds__(256, 3) void vq_main(const float* __restrict__ x,
                                                  const float* __restrict__ W,
                                                  const unsigned short* __restrict__ Wb,
                                                  const float* __restrict__ nh,
                                                  float* __restrict__ out) {
    __shared__ unsigned short cb[2][8192];   // 2 x 16 KiB codebook chunks
    __shared__ float nhs[512];               // -0.5*||w||^2
    __shared__ float Xf[64 * 68];            // tokens fp32 [tok][d], pad 68; reused for output
    __shared__ int bkArr[64];

    const int tid = threadIdx.x;
    const int bid = blockIdx.x;
    const int b = bid >> 6;                  // batch
    const int p0 = (bid & 63) << 6;          // spatial block base
    const int l = tid & 63;
    const int wv = tid >> 6;

    // ---- prologue: issue all global loads, then LDS writes ----
    f32x4 st[4];                             // codebook chunk 0 (16 KiB linear image)
    {
        const f32x4* src = (const f32x4*)Wb;
        #pragma unroll
        for (int i = 0; i < 4; ++i) st[i] = src[i * 256 + tid];
    }
    f32x4 nh4;
    if (tid < 128) nh4 = ((const f32x4*)nh)[tid];
    f32x4 xv[4];                             // x: c = tid>>4 + 16i, p4 = (tid&15)*4
    #pragma unroll
    for (int i = 0; i < 4; ++i) {
        int c = (tid >> 4) + i * 16;
        xv[i] = *(const f32x4*)(x + (size_t)(b * 64 + c) * HW_ + p0 + (tid & 15) * 4);
    }
    {
        f32x4* dst = (f32x4*)&cb[0][0];
        #pragma unroll
        for (int i = 0; i < 4; ++i) dst[i * 256 + tid] = st[i];
    }
    if (tid < 128) ((f32x4*)nhs)[tid] = nh4;
    #pragma unroll
    for (int i = 0; i < 4; ++i) {
        int c = (tid >> 4) + i * 16;
        int p4 = (tid & 15) * 4;
        #pragma unroll
        for (int j = 0; j < 4; ++j) Xf[(p4 + j) * 68 + c] = xv[i][j];
    }
    __syncthreads();

    const int g = l >> 4;                    // k-dim group 0..3
    const int tokw = l & 15;
    const int tok = wv * 16 + tokw;

    // B fragments: X[tok][d], d = s*32 + g*8 + e
    short8 bfrag[2];
    #pragma unroll
    for (int s = 0; s < 2; ++s) {
        f32x4 v0 = *(const f32x4*)(&Xf[tok * 68 + s * 32 + g * 8]);
        f32x4 v1 = *(const f32x4*)(&Xf[tok * 68 + s * 32 + g * 8 + 4]);
        #pragma unroll
        for (int j = 0; j < 4; ++j) {
            bfrag[s][j]     = (short)f2bf(v0[j]);
            bfrag[s][j + 4] = (short)f2bf(v1[j]);
        }
    }

    // ---- main loop: 4 chunks x 8 ktiles; scores packed to f16 ----
    float m = -3.4e38f;
    unsigned pk[64];
    #pragma unroll
    for (int c = 0; c < 4; ++c) {
        const int cur = c & 1;
        f32x4 sn[4];
        if (c < 3) {                          // issue next-chunk loads early (T14)
            const f32x4* src = (const f32x4*)(Wb + (c + 1) * 8192);
            #pragma unroll
            for (int i = 0; i < 4; ++i) sn[i] = src[i * 256 + tid];
        }
        #pragma unroll
        for (int tt = 0; tt < 8; ++tt) {
            const int r = tt * 16 + tokw;
            // swizzled read: elem = r*64 + 8*((g+4s) ^ (r&7))
            const int i0 = r * 64 + 8 * ((g)     ^ (r & 7));
            const int i1 = r * 64 + 8 * ((g + 4) ^ (r & 7));
            short8 a0 = *(const short8*)(&cb[cur][i0]);
            short8 a1 = *(const short8*)(&cb[cur][i1]);
            f32x4 acc = *(const f32x4*)(&nhs[c * 128 + tt * 16 + g * 4]);
            acc = __builtin_amdgcn_mfma_f32_16x16x32_bf16(a0, bfrag[0], acc, 0, 0, 0);
            acc = __builtin_amdgcn_mfma_f32_16x16x32_bf16(a1, bfrag[1], acc, 0, 0, 0);
            m = fmaxf(m, fmaxf(fmaxf(acc[0], acc[1]), fmaxf(acc[2], acc[3])));
            const int t = c * 8 + tt;
            h2 ph0 = __builtin_amdgcn_cvt_pkrtz(acc[0], acc[1]);
            h2 ph1 = __builtin_amdgcn_cvt_pkrtz(acc[2], acc[3]);
            pk[t * 2]     = __builtin_bit_cast(unsigned, ph0);
            pk[t * 2 + 1] = __builtin_bit_cast(unsigned, ph1);
        }
        if (c < 3) {                          // write-late into the other buffer
            f32x4* dst = (f32x4*)&cb[cur ^ 1][0];
            #pragma unroll
            for (int i = 0; i < 4; ++i) dst[i * 256 + tid] = sn[i];
        }
        __syncthreads();
    }

    // ---- per-token max + candidate scan ----
    m = fmaxf(m, __shfl_xor(m, 16));
    m = fmaxf(m, __shfl_xor(m, 32));
    const float thr = m - MARGIN;

    uint64_t c0m = 0, c1m = 0;
    int cnt = 0;
    #pragma unroll
    for (int t = 0; t < 32; ++t) {
        #pragma unroll
        for (int hh = 0; hh < 2; ++hh) {
            h2 ph = __builtin_bit_cast(h2, pk[t * 2 + hh]);
            float s0 = (float)ph[0], s1 = (float)ph[1];
            int slot = t * 4 + hh * 2;
            if (s0 >= thr) {
                ++cnt;
                if (t < 16) c0m |= 1ull << slot; else c1m |= 1ull << (slot - 64);
            }
            if (s1 >= thr) {
                ++cnt;
                if (t < 16) c0m |= 1ull << (slot + 1); else c1m |= 1ull << (slot + 1 - 64);
            }
        }
    }
    int cnt4 = cnt;
    cnt4 += __shfl_xor(cnt4, 16);
    cnt4 += __shfl_xor(cnt4, 32);

    // singleton fast path: the lone candidate is provably the exact argmin
    int klocal = 0x7fffffff;
    if (cnt == 1) {
        int slot = c0m ? __builtin_ctzll(c0m) : 64 + __builtin_ctzll(c1m);
        klocal = (slot >> 2) * 16 + g * 4 + (slot & 3);
    }
    int kmin = klocal;
    kmin = min(kmin, __shfl_xor(kmin, 16));
    kmin = min(kmin, __shfl_xor(kmin, 32));

    // multi-candidate: exact fp64 sum((x-w)^2), wave-cooperative
    double bd = 1.0e308;
    int bkm = 0x7fffffff;
    const bool multi = (cnt4 > 1);
    if (!multi) { c0m = 0; c1m = 0; }
    uint64_t wmask = __ballot((c0m | c1m) != 0ull);
    while (wmask) {
        int L = __builtin_ctzll(wmask);
        wmask &= wmask - 1;
        uint64_t m0 = __shfl(c0m, L);
        uint64_t m1 = __shfl(c1m, L);
        int gL = L >> 4;
        int tokL = wv * 16 + (L & 15);
        double xvd = (double)Xf[tokL * 68 + l];
        while (m0 | m1) {
            int k;
            if (m0) {
                int slot = __builtin_ctzll(m0); m0 &= m0 - 1;
                k = (slot >> 2) * 16 + gL * 4 + (slot & 3);
            } else {
                int slot = __builtin_ctzll(m1); m1 &= m1 - 1;
                k = ((slot >> 2) + 16) * 16 + gL * 4 + (slot & 3);
            }
            double dl = xvd - (double)W[k * 64 + l];
            double p = dl * dl;
            #pragma unroll
            for (int off = 1; off < 64; off <<= 1) p += __shfl_xor(p, off);
            if (l == L && (p < bd || (p == bd && k < bkm))) { bd = p; bkm = k; }
        }
    }
    {
        double od = __shfl_xor(bd, 16); int ok = __shfl_xor(bkm, 16);
        if (od < bd || (od == bd && ok < bkm)) { bd = od; bkm = ok; }
        od = __shfl_xor(bd, 32); ok = __shfl_xor(bkm, 32);
        if (od < bd || (od == bd && ok < bkm)) { bd = od; bkm = ok; }
    }
    const int bk = multi ? bkm : kmin;

    if (g == 0) bkArr[wv * 16 + tokw] = bk;
    __syncthreads();

    // ---- output: gather W[bk] into Xf as [d][tok], then coalesced NCHW store ----
    {
        int tk = tid >> 2;
        int part = tid & 3;
        int k = bkArr[tk];
        #pragma unroll
        for (int j = 0; j < 4; ++j) {
            f32x4 v = *(const f32x4*)(W + k * 64 + part * 16 + j * 4);
            #pragma unroll
            for (int cc = 0; cc < 4; ++cc)
                Xf[(part * 16 + j * 4 + cc) * 68 + tk] = v[cc];
        }
    }
    __syncthreads();
    #pragma unroll
    for (int i = 0; i < 4; ++i) {
        int d = (tid >> 4) + i * 16;
        int p4 = (tid & 15) * 4;
        f32x4 v = *(const f32x4*)(&Xf[d * 68 + p4]);
        *(f32x4*)(out + (size_t)(b * 64 + d) * HW_ + p0 + p4) = v;
    }
}

extern "C" void kernel_launch(void* const* d_in, const int* in_sizes, int n_in,
                              void* d_out, int out_size, void* d_ws, size_t ws_size,
                              hipStream_t stream) {
    const float* x = (const float*)d_in[0];
    const float* W = (const float*)d_in[1];
    unsigned short* Wb = (unsigned short*)d_ws;            // 64 KiB swizzled bf16 codebook
    float* nh = (float*)((char*)d_ws + K_ * D_ * 2);       // 512 f32
    vq_prep<<<K_, 64, 0, stream>>>(W, Wb, nh);
    vq_main<<<2048, 256, 0, stream>>>(x, W, Wb, nh, (float*)d_out);
}